// Round 7
// baseline (561.006 us; speedup 1.0000x reference)
//
#include <hip/hip_runtime.h>

#define NROWS 8192
#define DIM 512
#define HID 1024
#define BN_EPS 1e-5f

typedef unsigned short ushort_t;
typedef __attribute__((ext_vector_type(8))) __bf16 bf16x8;
typedef __attribute__((ext_vector_type(4))) float f32x4;

union U4 {
    uint4 u;
    bf16x8 b;
    ushort_t s[8];
};

static __device__ __forceinline__ float b2f(ushort_t u) {
    union { float f; unsigned int i; } c;
    c.i = ((unsigned int)u) << 16;
    return c.f;
}

static __device__ __forceinline__ ushort_t f2b(float f) {
    union { float f; unsigned int i; } c;
    c.f = f;
    unsigned int i = c.i;
    unsigned int r = (i + 0x7FFFu + ((i >> 16) & 1u)) >> 16;
    return (ushort_t)r;
}

// ---------------------------------------------------------------------------
// 1) merged prep (grid 1280 x 256):
//  blocks 0..255  : partial colsum  hs_part[bid][d] = sum of 32 rows; hB=bf16(h)
//  blocks 256..767: W1T[c][r] = bf16(f1w[r][c] * a1[r])
//  blocks 768..1279: W2T[c][r] = bf16(f2w[r][c])
// No memset needed: hs_part fully overwritten.
__global__ void prep_kernel(const float* __restrict__ h, float* __restrict__ hs_part,
                            ushort_t* __restrict__ hB,
                            const float* __restrict__ f1w,
                            const float* __restrict__ g1, const float* __restrict__ v1,
                            const float* __restrict__ f2w,
                            ushort_t* __restrict__ W1T, ushort_t* __restrict__ W2T) {
    __shared__ float tile[32][33];
    int bid = blockIdx.x;
    if (bid < 256) {
        int t = threadIdx.x;
        int col0 = (t & 127) * 4;
        int rsub = t >> 7;
        int row0 = bid * 32;
        float acc[4] = {0.f, 0.f, 0.f, 0.f};
        for (int r = 0; r < 16; ++r) {
            int row = row0 + r * 2 + rsub;
            float4 v = *(const float4*)(h + (size_t)row * DIM + col0);
            acc[0] += v.x; acc[1] += v.y; acc[2] += v.z; acc[3] += v.w;
            ushort_t bv[4];
            bv[0] = f2b(v.x); bv[1] = f2b(v.y); bv[2] = f2b(v.z); bv[3] = f2b(v.w);
            *(uint2*)(hB + (size_t)row * DIM + col0) = *(uint2*)bv;
        }
        // two row-subgroups -> combine via LDS then one write per col
        __shared__ float part[2][512];
#pragma unroll
        for (int j = 0; j < 4; ++j) part[rsub][col0 + j] = acc[j];
        __syncthreads();
        if (rsub == 0) {
#pragma unroll
            for (int j = 0; j < 4; ++j)
                hs_part[(size_t)bid * 512 + col0 + j] = part[0][col0 + j] + part[1][col0 + j];
        }
    } else if (bid < 768) {
        int b = bid - 256;
        int tx = threadIdx.x & 31, ty = threadIdx.x >> 5;
        int bx = (b & 31) * 32, by = (b >> 5) * 32;
#pragma unroll
        for (int i = 0; i < 32; i += 8)
            tile[ty + i][tx] = f1w[(size_t)(by + ty + i) * HID + bx + tx];
        __syncthreads();
        int r = by + tx;
        float a1 = g1[r] * rsqrtf(v1[r] + BN_EPS);
#pragma unroll
        for (int i = 0; i < 32; i += 8)
            W1T[(size_t)(bx + ty + i) * DIM + r] = f2b(tile[tx][ty + i] * a1);
    } else {
        int b2 = bid - 768;
        int tx = threadIdx.x & 31, ty = threadIdx.x >> 5;
        int bx = (b2 & 15) * 32, by = (b2 >> 4) * 32;
#pragma unroll
        for (int i = 0; i < 32; i += 8)
            tile[ty + i][tx] = f2w[(size_t)(by + ty + i) * DIM + bx + tx];
        __syncthreads();
#pragma unroll
        for (int i = 0; i < 32; i += 8)
            W2T[(size_t)(bx + ty + i) * HID + by + tx] = f2b(tile[tx][ty + i]);
    }
}

// ---------------------------------------------------------------------------
// 2) fused chain (grid 32 x 256). Every block redundantly computes:
//    hs = sum of hs_part;  s = hs@vw + 8192*vb;  t = s@ow + ob;
//    q0 = t*a1 + (b1 - m1*a1).  Then block b computes b1P cols [b*32, b*32+32):
//    b1P[c] = f1b[c] + sum_k q0[k]*f1w[k*1024+c].
__global__ void chain_kernel(const float* __restrict__ hs_part,
                             const float* __restrict__ vw, const float* __restrict__ vb,
                             const float* __restrict__ ow, const float* __restrict__ ob,
                             const float* __restrict__ f1w, const float* __restrict__ f1b,
                             const float* __restrict__ g1, const float* __restrict__ b1,
                             const float* __restrict__ m1, const float* __restrict__ v1,
                             float* __restrict__ b1P) {
    __shared__ float sh[512];
    __shared__ float red[8][32];
    int t = threadIdx.x;
    // 1) reduce partials
#pragma unroll
    for (int i = 0; i < 2; ++i) {
        int c = t + i * 256;
        float a = 0.f;
        for (int r = 0; r < 256; ++r) a += hs_part[(size_t)r * 512 + c];
        sh[c] = a;
    }
    __syncthreads();
    // 2) s = hs@vw + N*vb
    float sv[2];
#pragma unroll
    for (int i = 0; i < 2; ++i) {
        int c = t + i * 256;
        float a = 8192.0f * vb[c];
        for (int k = 0; k < 512; ++k) a += sh[k] * vw[(size_t)k * 512 + c];
        sv[i] = a;
    }
    __syncthreads();
    sh[t] = sv[0]; sh[t + 256] = sv[1];
    __syncthreads();
    // 3) t = s@ow + ob, then q0
    float tv[2];
#pragma unroll
    for (int i = 0; i < 2; ++i) {
        int c = t + i * 256;
        float a = ob[c];
        for (int k = 0; k < 512; ++k) a += sh[k] * ow[(size_t)k * 512 + c];
        tv[i] = a;
    }
    __syncthreads();
#pragma unroll
    for (int i = 0; i < 2; ++i) {
        int c = t + i * 256;
        float a1 = g1[c] * rsqrtf(v1[c] + BN_EPS);
        sh[c] = tv[i] * a1 + (b1[c] - m1[c] * a1);
    }
    __syncthreads();
    // 4) b1P for this block's 32 columns
    int col = blockIdx.x * 32 + (t & 31);
    int ks = t >> 5;
    float acc = 0.f;
    for (int ki = 0; ki < 64; ++ki) {
        int k = ks * 64 + ki;
        acc += sh[k] * f1w[(size_t)k * HID + col];
    }
    red[ks][t & 31] = acc;
    __syncthreads();
    if (ks == 0) {
        float tot = f1b[col];
#pragma unroll
        for (int r = 0; r < 8; ++r) tot += red[r][t & 31];
        b1P[col] = tot;
    }
}

// ---------------------------------------------------------------------------
// 3) GEMM1: Z = relu(hB @ W1T^T + b1P).  128x128 tile, BK=64 (32 MFMA/barrier),
// padded LDS (LDA=72), 256 threads = 4 waves (2x2 of 64x64), wave 4x4 MFMA.
__global__ __launch_bounds__(256) void gemm1_kernel(const ushort_t* __restrict__ A,
                                                    const ushort_t* __restrict__ BT,
                                                    const float* __restrict__ bias,
                                                    ushort_t* __restrict__ C) {
    const int K = DIM, Nn = HID, LDA = 72;
    __shared__ ushort_t As[128 * LDA];
    __shared__ ushort_t Bs[128 * LDA];
    int tid = threadIdx.x;
    int lane = tid & 63, w = tid >> 6;
    int wm = (w & 1) * 64, wn = (w >> 1) * 64;
    int bm = blockIdx.y * 128, bn = blockIdx.x * 128;

    f32x4 acc[4][4] = {};

    int r0 = tid >> 2, kc0 = (tid & 3) * 8;
    int r1 = r0 + 64;

    for (int k0 = 0; k0 < K; k0 += 64) {
        __syncthreads();
        uint4 a00 = *(const uint4*)(A + (size_t)(bm + r0) * K + k0 + kc0);
        uint4 a01 = *(const uint4*)(A + (size_t)(bm + r0) * K + k0 + kc0 + 32);
        uint4 a10 = *(const uint4*)(A + (size_t)(bm + r1) * K + k0 + kc0);
        uint4 a11 = *(const uint4*)(A + (size_t)(bm + r1) * K + k0 + kc0 + 32);
        uint4 b00 = *(const uint4*)(BT + (size_t)(bn + r0) * K + k0 + kc0);
        uint4 b01 = *(const uint4*)(BT + (size_t)(bn + r0) * K + k0 + kc0 + 32);
        uint4 b10 = *(const uint4*)(BT + (size_t)(bn + r1) * K + k0 + kc0);
        uint4 b11 = *(const uint4*)(BT + (size_t)(bn + r1) * K + k0 + kc0 + 32);
        *(uint4*)(As + r0 * LDA + kc0) = a00;
        *(uint4*)(As + r0 * LDA + kc0 + 32) = a01;
        *(uint4*)(As + r1 * LDA + kc0) = a10;
        *(uint4*)(As + r1 * LDA + kc0 + 32) = a11;
        *(uint4*)(Bs + r0 * LDA + kc0) = b00;
        *(uint4*)(Bs + r0 * LDA + kc0 + 32) = b01;
        *(uint4*)(Bs + r1 * LDA + kc0) = b10;
        *(uint4*)(Bs + r1 * LDA + kc0 + 32) = b11;
        __syncthreads();

#pragma unroll
        for (int s = 0; s < 2; ++s) {
            int koff = (lane >> 4) * 8 + s * 32;
            bf16x8 af[4], bfr[4];
#pragma unroll
            for (int i = 0; i < 4; ++i) {
                U4 t;
                t.u = *(const uint4*)(As + (wm + i * 16 + (lane & 15)) * LDA + koff);
                af[i] = t.b;
            }
#pragma unroll
            for (int j = 0; j < 4; ++j) {
                U4 t;
                t.u = *(const uint4*)(Bs + (wn + j * 16 + (lane & 15)) * LDA + koff);
                bfr[j] = t.b;
            }
#pragma unroll
            for (int i = 0; i < 4; ++i)
#pragma unroll
                for (int j = 0; j < 4; ++j)
                    acc[i][j] = __builtin_amdgcn_mfma_f32_16x16x32_bf16(af[i], bfr[j], acc[i][j], 0, 0, 0);
        }
    }

    // epilogue: D layout row=(lane>>4)*4+r, col=lane&15 (m91-verified)
#pragma unroll
    for (int i = 0; i < 4; ++i) {
        int row0 = bm + wm + i * 16 + (lane >> 4) * 4;
#pragma unroll
        for (int j = 0; j < 4; ++j) {
            int col = bn + wn + j * 16 + (lane & 15);
            float bv = bias[col];
#pragma unroll
            for (int r = 0; r < 4; ++r) {
                float v = fmaxf(acc[i][j][r] + bv, 0.f);
                C[(size_t)(row0 + r) * Nn + col] = f2b(v);
            }
        }
    }
}

// ---------------------------------------------------------------------------
// 4) GEMM2 + fused epilogue:
// out = ((hB*a1 + q0) + (Z @ W2T^T) + fb2) * a2 + c2,  consts inline.
// 128x64 tile, BK=64, padded LDS, 4 waves (2x2 of 64x32), grid (8, 64).
__global__ __launch_bounds__(256) void gemm2_kernel(const ushort_t* __restrict__ A,
                                                    const ushort_t* __restrict__ BT,
                                                    const float* __restrict__ bias,
                                                    const ushort_t* __restrict__ hB,
                                                    const float* __restrict__ tvec,
                                                    const float* __restrict__ g1,
                                                    const float* __restrict__ b1,
                                                    const float* __restrict__ m1,
                                                    const float* __restrict__ v1,
                                                    const float* __restrict__ g2,
                                                    const float* __restrict__ b2,
                                                    const float* __restrict__ m2,
                                                    const float* __restrict__ v2,
                                                    float* __restrict__ out) {
    const int K = HID, LDA = 72;
    __shared__ ushort_t As[128 * LDA];
    __shared__ ushort_t Bs[64 * LDA];
    int tid = threadIdx.x;
    int lane = tid & 63, w = tid >> 6;
    int wm = (w & 1) * 64, wn = (w >> 1) * 32;
    int bm = blockIdx.y * 128, bn = blockIdx.x * 64;

    f32x4 acc[4][2] = {};

    int r0 = tid >> 2, kc0 = (tid & 3) * 8;
    int r1 = r0 + 64;

    for (int k0 = 0; k0 < K; k0 += 64) {
        __syncthreads();
        uint4 a00 = *(const uint4*)(A + (size_t)(bm + r0) * K + k0 + kc0);
        uint4 a01 = *(const uint4*)(A + (size_t)(bm + r0) * K + k0 + kc0 + 32);
        uint4 a10 = *(const uint4*)(A + (size_t)(bm + r1) * K + k0 + kc0);
        uint4 a11 = *(const uint4*)(A + (size_t)(bm + r1) * K + k0 + kc0 + 32);
        uint4 b00 = *(const uint4*)(BT + (size_t)(bn + r0) * K + k0 + kc0);
        uint4 b01 = *(const uint4*)(BT + (size_t)(bn + r0) * K + k0 + kc0 + 32);
        *(uint4*)(As + r0 * LDA + kc0) = a00;
        *(uint4*)(As + r0 * LDA + kc0 + 32) = a01;
        *(uint4*)(As + r1 * LDA + kc0) = a10;
        *(uint4*)(As + r1 * LDA + kc0 + 32) = a11;
        *(uint4*)(Bs + r0 * LDA + kc0) = b00;
        *(uint4*)(Bs + r0 * LDA + kc0 + 32) = b01;
        __syncthreads();

#pragma unroll
        for (int s = 0; s < 2; ++s) {
            int koff = (lane >> 4) * 8 + s * 32;
            bf16x8 af[4], bfr[2];
#pragma unroll
            for (int i = 0; i < 4; ++i) {
                U4 t;
                t.u = *(const uint4*)(As + (wm + i * 16 + (lane & 15)) * LDA + koff);
                af[i] = t.b;
            }
#pragma unroll
            for (int j = 0; j < 2; ++j) {
                U4 t;
                t.u = *(const uint4*)(Bs + (wn + j * 16 + (lane & 15)) * LDA + koff);
                bfr[j] = t.b;
            }
#pragma unroll
            for (int i = 0; i < 4; ++i)
#pragma unroll
                for (int j = 0; j < 2; ++j)
                    acc[i][j] = __builtin_amdgcn_mfma_f32_16x16x32_bf16(af[i], bfr[j], acc[i][j], 0, 0, 0);
        }
    }

#pragma unroll
    for (int i = 0; i < 4; ++i) {
        int row0 = bm + wm + i * 16 + (lane >> 4) * 4;
#pragma unroll
        for (int j = 0; j < 2; ++j) {
            int col = bn + wn + j * 16 + (lane & 15);
            float a1c = g1[col] * rsqrtf(v1[col] + BN_EPS);
            float q0c = tvec[col] * a1c + (b1[col] - m1[col] * a1c);
            float a2c = g2[col] * rsqrtf(v2[col] + BN_EPS);
            float c2c = b2[col] - m2[col] * a2c;
            float bv = bias[col];
#pragma unroll
            for (int r = 0; r < 4; ++r) {
                int row = row0 + r;
                float x1 = b2f(hB[(size_t)row * DIM + col]) * a1c + q0c;
                out[(size_t)row * DIM + col] = (x1 + acc[i][j][r] + bv) * a2c + c2c;
            }
        }
    }
}

// ---------------------------------------------------------------------------
// gemm2 needs tvec (the t vector) for q0; chain writes q0 into... we pass the
// raw pieces instead: recompute t via chain? Simpler: chain also writes tvec.
__global__ void chain_tvec_kernel(const float* __restrict__ hs_part,
                                  const float* __restrict__ vw, const float* __restrict__ vb,
                                  const float* __restrict__ ow, const float* __restrict__ ob,
                                  float* __restrict__ tvec) {
    __shared__ float sh[512];
    int t = threadIdx.x;
#pragma unroll
    for (int i = 0; i < 2; ++i) {
        int c = t + i * 256;
        float a = 0.f;
        for (int r = 0; r < 256; ++r) a += hs_part[(size_t)r * 512 + c];
        sh[c] = a;
    }
    __syncthreads();
    float sv[2];
#pragma unroll
    for (int i = 0; i < 2; ++i) {
        int c = t + i * 256;
        float a = 8192.0f * vb[c];
        for (int k = 0; k < 512; ++k) a += sh[k] * vw[(size_t)k * 512 + c];
        sv[i] = a;
    }
    __syncthreads();
    sh[t] = sv[0]; sh[t + 256] = sv[1];
    __syncthreads();
#pragma unroll
    for (int i = 0; i < 2; ++i) {
        int c = t + i * 256;
        float a = ob[c];
        for (int k = 0; k < 512; ++k) a += sh[k] * ow[(size_t)k * 512 + c];
        tvec[c] = a;
    }
}

// ---------------------------------------------------------------------------
extern "C" void kernel_launch(void* const* d_in, const int* in_sizes, int n_in,
                              void* d_out, int out_size, void* d_ws, size_t ws_size,
                              hipStream_t stream) {
    // inputs (all fp32): 0:A 1:h 2:qw 3:qb 4:kw 5:kb 6:vw 7:vb 8:ow 9:ob
    // 10:f1w 11:f1b 12:f2w 13:f2b 14-17:bn1 g,b,m,v 18-21:bn2 g,b,m,v
    const float* h = (const float*)d_in[1];
    const float* vw = (const float*)d_in[6];
    const float* vb = (const float*)d_in[7];
    const float* ow = (const float*)d_in[8];
    const float* ob = (const float*)d_in[9];
    const float* f1w = (const float*)d_in[10];
    const float* f1b = (const float*)d_in[11];
    const float* f2w = (const float*)d_in[12];
    const float* fb2 = (const float*)d_in[13];
    const float* g1 = (const float*)d_in[14];
    const float* b1 = (const float*)d_in[15];
    const float* m1 = (const float*)d_in[16];
    const float* v1 = (const float*)d_in[17];
    const float* g2 = (const float*)d_in[18];
    const float* b2 = (const float*)d_in[19];
    const float* m2 = (const float*)d_in[20];
    const float* v2 = (const float*)d_in[21];
    float* out = (float*)d_out;

    char* ws = (char*)d_ws;
    float* hs_part = (float*)(ws + 0);     // [256][512] f32, 512 KB
    float* tBuf = (float*)(ws + 524288);   // 512 f32
    float* b1P = (float*)(ws + 528384);    // 1024 f32
    ushort_t* W1T = (ushort_t*)(ws + 540672);              // [1024][512] bf16, 1 MB
    ushort_t* W2T = (ushort_t*)(ws + 540672 + 1048576);    // [512][1024] bf16, 1 MB
    ushort_t* Z = (ushort_t*)(ws + 540672 + 2097152);      // [8192][1024] bf16, 16 MB
    ushort_t* hB = (ushort_t*)(ws + 540672 + 2097152 + 16777216); // [8192][512] bf16, 8 MB

    prep_kernel<<<1280, 256, 0, stream>>>(h, hs_part, hB, f1w, g1, v1, f2w, W1T, W2T);
    chain_tvec_kernel<<<1, 256, 0, stream>>>(hs_part, vw, vb, ow, ob, tBuf);
    chain_kernel<<<32, 256, 0, stream>>>(hs_part, vw, vb, ow, ob, f1w, f1b,
                                         g1, b1, m1, v1, b1P);
    gemm1_kernel<<<dim3(8, 64), 256, 0, stream>>>(hB, W1T, b1P, Z);
    gemm2_kernel<<<dim3(8, 64), 256, 0, stream>>>(Z, W2T, fb2, hB, tBuf,
                                                  g1, b1, m1, v1, g2, b2, m2, v2, out);
}